// Round 7
// baseline (57.095 us; speedup 1.0000x reference)
//
#include <hip/hip_runtime.h>

#define N_IMG 8
#define CIN   128
#define H_IN  56
#define W_IN  56
#define COUT  128
#define HW    3136
#define XT_B    6422528ULL          // 8*3136*128*2  (NHWC f16)
#define WR2_B   294912ULL           // 144*128*8*2   (B fragment-linear f16)
#define AIMG_B  7225344ULL          // 49*18*8192    (im2col A per image)

typedef __attribute__((ext_vector_type(8))) short short8;
typedef __attribute__((ext_vector_type(4))) float f32x4;
typedef _Float16 h8 __attribute__((ext_vector_type(8)));

__device__ __forceinline__ unsigned short hb(float f) {
    _Float16 h = (_Float16)f;
    return __builtin_bit_cast(unsigned short, h);
}
__device__ __forceinline__ h8 splat8(unsigned short b) {
    _Float16 s = __builtin_bit_cast(_Float16, b);
    return (h8){s, s, s, s, s, s, s, s};
}
__device__ __forceinline__ void gload16(const void* g, void* l) {
    __builtin_amdgcn_global_load_lds(
        (const __attribute__((address_space(1))) unsigned int*)g,
        (__attribute__((address_space(3))) unsigned int*)l, 16, 0, 0);
}

// blocks 0..783: x (N,C,H,W) f32 -> xt (N,H,W,C) f16
// blocks 784..855: weight -> wr2[k8g(144)][cout(128)][8] f16, k8g = tap*16+cg
__global__ __launch_bounds__(256) void prep_kernel(const float* __restrict__ x,
                                                   const float* __restrict__ w,
                                                   unsigned short* __restrict__ xt,
                                                   unsigned short* __restrict__ wr2) {
    int b = blockIdx.x;
    int tid = threadIdx.x;
    if (b < 784) {
        int c = tid & 127;
        int half = tid >> 7;
        int n = b / 98;
        int hw0 = (b - n * 98) * 32 + half * 16;
        const float* xp = x + ((size_t)(n * CIN + c)) * HW + hw0;
        unsigned short* op = xt + ((size_t)n * HW + hw0) * CIN + c;
#pragma unroll
        for (int r = 0; r < 16; ++r) op[r * CIN] = hb(xp[r]);
    } else {
        int idx = (b - 784) * 256 + tid;        // 0..18431 = 144*128
        int k8g = idx >> 7;                     // 0..143
        int cout = idx & 127;
        int tap = k8g >> 4;
        int cg = k8g & 15;
        short8 v;
#pragma unroll
        for (int j = 0; j < 8; ++j)
            v[j] = (short)hb(w[((size_t)cout * CIN + cg * 8 + j) * 9 + tap]);
        *(short8*)(wr2 + (size_t)idx * 8) = v;
    }
}

// K1: gather + bilinear interp -> A[nl][mt(49)][k8g(144)][px64][8] f16
__global__ __launch_bounds__(256) void interp_kernel(
    const float* __restrict__ offset, const unsigned short* __restrict__ xth,
    unsigned short* __restrict__ Abuf, int n0, int nmask, int nshift)
{
    __shared__ int4    lin_lds[144];
    __shared__ ushort4 wtp[144];
    int tid = threadIdx.x;
    int orig = blockIdx.x;                 // 196*NB blocks, 16 px each
    int nl = orig & nmask;
    int t16 = orig >> nshift;
    int n = n0 + nl;
    int hw0 = t16 << 4;

    if (tid < 144) {                        // 9 taps x 16 px params
        int tap = tid >> 4;
        int pl = tid & 15;
        int hw = hw0 + pl;
        int ho = hw / 56, wo = hw - ho * 56;
        const float* offp = offset + ((size_t)n * 18 + tap * 2) * HW + hw;
        float offy = offp[0], offx = offp[HW];
        int ki = tap / 3, kj = tap - ki * 3;
        float py = (float)(ho - 1 + ki) + offy;
        float pxf = (float)(wo - 1 + kj) + offx;
        float y0f = floorf(py), x0f = floorf(pxf);
        float wy = py - y0f, wx = pxf - x0f;
        int y0 = (int)y0f, x0 = (int)x0f, y1 = y0 + 1, x1 = x0 + 1;
        bool vy0 = (y0 >= 0) && (y0 < H_IN);
        bool vy1 = (y1 >= 0) && (y1 < H_IN);
        bool vx0 = (x0 >= 0) && (x0 < W_IN);
        bool vx1 = (x1 >= 0) && (x1 < W_IN);
        int cy0 = min(max(y0, 0), 55), cy1 = min(max(y1, 0), 55);
        int cx0 = min(max(x0, 0), 55), cx1 = min(max(x1, 0), 55);
        int4 lv;
        lv.x = (cy0 * 56 + cx0) << 8;       // 256B per pixel block (128ch f16)
        lv.y = (cy0 * 56 + cx1) << 8;
        lv.z = (cy1 * 56 + cx0) << 8;
        lv.w = (cy1 * 56 + cx1) << 8;
        lin_lds[tid] = lv;
        ushort4 wp;
        wp.x = hb((vy0 && vx0) ? (1.f - wy) * (1.f - wx) : 0.f);
        wp.y = hb((vy0 && vx1) ? (1.f - wy) * wx : 0.f);
        wp.z = hb((vy1 && vx0) ? wy * (1.f - wx) : 0.f);
        wp.w = hb((vy1 && vx1) ? wy * wx : 0.f);
        wtp[tid] = wp;
    }
    __syncthreads();

    int u  = tid & 15;                      // channel chunk 0..15 (8 ch)
    int px = tid >> 4;                      // pixel 0..15
    const char* xim = (const char*)xth + (size_t)n * (HW * 256) + (u << 4);
    int p = hw0 + px;
    int mt = p >> 6, px64 = p & 63;
    char* Ab = (char*)Abuf + (size_t)nl * AIMG_B + (size_t)mt * 147456 + px64 * 16;

#pragma unroll 3
    for (int tap = 0; tap < 9; ++tap) {
        int4 lv = lin_lds[tap * 16 + px];
        ushort4 wp = wtp[tap * 16 + px];
        h8 v00 = *(const h8*)(xim + lv.x);
        h8 v01 = *(const h8*)(xim + lv.y);
        h8 v10 = *(const h8*)(xim + lv.z);
        h8 v11 = *(const h8*)(xim + lv.w);
        h8 r = v00 * splat8(wp.x) + v01 * splat8(wp.y)
             + v10 * splat8(wp.z) + v11 * splat8(wp.w);
        int k8g = (tap << 4) + u;
        *(h8*)(Ab + ((size_t)k8g << 10)) = r;
    }
}

// K2: GEMM  out[n][cout][hw] = A @ wr2^T + bias + x2, ReLU
__global__ __launch_bounds__(256) void gemm_kernel(
    const unsigned short* __restrict__ Abuf, const unsigned short* __restrict__ wr2,
    const float* __restrict__ bias, const float* __restrict__ x2,
    float* __restrict__ out, int n0, int nmask, int nshift)
{
    __shared__ short albuf[2][4096];        // 8KB: [k8(8)][px64][8]
    __shared__ short blbuf[2][8192];        // 16KB: [k8(8)][cout128][8]
    int tid = threadIdx.x;
    int orig = blockIdx.x;                  // 49*NB blocks, 64 px each
    int nl = orig & nmask;
    int mt = orig >> nshift;
    int n = n0 + nl;
    const char* Ab = (const char*)Abuf + (size_t)nl * AIMG_B + (size_t)mt * 147456;
    const char* Bb = (const char*)wr2;

    auto STAGE = [&](int kit) {
        int buf = kit & 1;
        gload16(Ab + (size_t)kit * 8192 + tid * 16, (char*)&albuf[buf][0] + tid * 16);
        gload16(Ab + (size_t)kit * 8192 + 4096 + tid * 16, (char*)&albuf[buf][0] + 4096 + tid * 16);
#pragma unroll
        for (int q = 0; q < 4; ++q)
            gload16(Bb + (size_t)kit * 16384 + q * 4096 + tid * 16,
                    (char*)&blbuf[buf][0] + q * 4096 + tid * 16);
    };

    int lane = tid & 63, wv = tid >> 6;
    int llo = lane & 15, lhi = lane >> 4;
    f32x4 acc[8] = {};

    STAGE(0);
    __syncthreads();

    for (int kit = 0; kit < 18; ++kit) {
        if (kit < 17) STAGE(kit + 1);
        int buf = kit & 1;
        h8 a0 = *(const h8*)&albuf[buf][(lhi * 64 + wv * 16 + llo) * 8];
        h8 a1 = *(const h8*)&albuf[buf][((4 + lhi) * 64 + wv * 16 + llo) * 8];
#pragma unroll
        for (int f = 0; f < 8; ++f) {
            h8 b0 = *(const h8*)&blbuf[buf][(lhi * 128 + f * 16 + llo) * 8];
            h8 b1 = *(const h8*)&blbuf[buf][((4 + lhi) * 128 + f * 16 + llo) * 8];
            acc[f] = __builtin_amdgcn_mfma_f32_16x16x32_f16(a0, b0, acc[f], 0, 0, 0);
            acc[f] = __builtin_amdgcn_mfma_f32_16x16x32_f16(a1, b1, acc[f], 0, 0, 0);
        }
        __syncthreads();
    }

    // epilogue: + bias + x2, ReLU (layout proven in R3-R6)
    int hwb = mt * 64 + wv * 16 + lhi * 4;
#pragma unroll
    for (int f = 0; f < 8; ++f) {
        int cout = f * 16 + llo;
        float bb = bias[cout];
        size_t off = ((size_t)(n * COUT + cout)) * HW + hwb;
        f32x4 xv = *(const f32x4*)(x2 + off);
        f32x4 o;
#pragma unroll
        for (int r = 0; r < 4; ++r) {
            float v = acc[f][r] + bb + xv[r];
            o[r] = v > 0.f ? v : 0.f;
        }
        *(f32x4*)(out + off) = o;
    }
}

extern "C" void kernel_launch(void* const* d_in, const int* in_sizes, int n_in,
                              void* d_out, int out_size, void* d_ws, size_t ws_size,
                              hipStream_t stream) {
    const float* x      = (const float*)d_in[0];
    const float* offset = (const float*)d_in[1];
    const float* weight = (const float*)d_in[2];
    const float* bias   = (const float*)d_in[3];
    const float* x2     = (const float*)d_in[4];
    float* out = (float*)d_out;

    unsigned short* xt  = (unsigned short*)d_ws;
    unsigned short* wr2 = (unsigned short*)((char*)d_ws + XT_B);
    unsigned short* A   = (unsigned short*)((char*)d_ws + XT_B + WR2_B);

    size_t avail = ws_size > (XT_B + WR2_B) ? ws_size - XT_B - WR2_B : 0;
    int NB, nshift;
    if      (avail >= 8 * AIMG_B) { NB = 8; nshift = 3; }
    else if (avail >= 4 * AIMG_B) { NB = 4; nshift = 2; }
    else if (avail >= 2 * AIMG_B) { NB = 2; nshift = 1; }
    else                          { NB = 1; nshift = 0; }
    int nmask = NB - 1;

    prep_kernel<<<856, 256, 0, stream>>>(x, weight, xt, wr2);
    for (int b0 = 0; b0 < N_IMG; b0 += NB) {
        interp_kernel<<<196 * NB, 256, 0, stream>>>(offset, xt, A, b0, nmask, nshift);
        gemm_kernel<<<49 * NB, 256, 0, stream>>>(A, wr2, bias, x2, out, b0, nmask, nshift);
    }
}